// Round 8
// baseline (405.686 us; speedup 1.0000x reference)
//
#include <hip/hip_runtime.h>
#include <math.h>

// Problem constants (reference: B=8, C=32, O=32, H=256, W=256, K=5, pad=2)
constexpr int IMG_H = 256;
constexpr int IMG_W = 256;
constexpr int NB = 8;
constexpr int NC = 32;
constexpr int NO = 32;
constexpr int PLANE = IMG_H * IMG_W;          // 65536
constexpr int HALF = NB * NC * PLANE;         // 16,777,216 floats (64 MB)

// Wave-private tiling: each WAVE owns a 16x4 output tile; no __syncthreads.
// Halo region per wave: 8 rows x 24 cols, staged in wave-private LDS.
constexpr int WTW = 16;                       // wave tile width
constexpr int WTH = 4;                        // wave tile height
constexpr int RR = WTH + 4;                   // 8 region rows
constexpr int RC = 24;                        // region cols [w0-4, w0+20)
constexpr int RSB = RC * 8;                   // 192 B row stride ({P,V} f2/px)
constexpr int BUFB = RR * RSB;                // 1536 B per channel buffer
constexpr int WLDS = 2 * BUFB;                // 3072 B per wave (double buf)
constexpr int NWAVE = 4;                      // waves per block (independent)
constexpr int NT = NWAVE * 64;                // 256 threads
// grid: 16 x 64 wave-tiles per image x 8 images / 4 waves = 2048 blocks
constexpr int NBLK = (IMG_W / WTW) * (IMG_H / WTH) * NB / NWAVE;

#define EPSV 1e-20f

typedef float f4 __attribute__((ext_vector_type(4)));
typedef float f2 __attribute__((ext_vector_type(2)));

__device__ __forceinline__ float rcpf_(float x) { return __builtin_amdgcn_rcpf(x); }
__device__ __forceinline__ float softplusf_(float x) {
  return fmaxf(x, 0.0f) + log1pf(expf(-fabsf(x)));
}

// ws layout (floats): [0..31] wp, [32..831] sw (c-major, 25/ch),
// [832..1855] cwT[c][o] (transposed), [1856] sum(sw), [1857] sum(cw)
__global__ void weights_kernel(const float* __restrict__ wp_raw,
                               const float* __restrict__ sw_raw,
                               const float* __restrict__ cw_raw,
                               float* __restrict__ ws) {
  __shared__ float red[256];
  const int t = threadIdx.x;
  if (t < 32) ws[t] = softplusf_(wp_raw[t]);
  float ssum = 0.f;
  for (int i = t; i < NC * 25; i += 256) {
    float v = softplusf_(sw_raw[i]);
    ws[32 + i] = v;
    ssum += v;
  }
  float csum = 0.f;
  for (int i = t; i < NO * NC; i += 256) {
    float v = softplusf_(cw_raw[i]);
    int o = i >> 5, c = i & 31;
    ws[832 + c * NO + o] = v;  // transposed: [c][o]
    csum += v;
  }
  red[t] = ssum; __syncthreads();
  for (int off = 128; off; off >>= 1) { if (t < off) red[t] += red[t + off]; __syncthreads(); }
  const float S_sw = red[0];
  __syncthreads();
  red[t] = csum; __syncthreads();
  for (int off = 128; off; off >>= 1) { if (t < off) red[t] += red[t + off]; __syncthreads(); }
  if (t == 0) { ws[1856] = S_sw; ws[1857] = red[0]; }
}

// Pointwise gradient-propagation math. Requires cdv/cgv pre-zeroed for
// OOB pixels (then Pv = Vv = 0 follows algebraically, no NaN).
__device__ __forceinline__ void pointwise_pv(
    float dv, float cdv, float gxv, float cgv, int gw,
    float wpc, float inv_wp1, float& Pv, float& Vv) {
  // d_left = d with last col zeroed; d_right = d with first col zeroed
  float dl  = (gw == IMG_W - 1) ? 0.f : dv;
  float cdl = (gw == IMG_W - 1) ? 0.f : cdv;
  float dr  = (gw == 0) ? 0.f : dv;
  float cdr = (gw == 0) ? 0.f : cdv;
  float cfd = cdl * cdr;                                      // cgx_from_ds
  float height = (cdl * dl + cdr * dr) * rcpf_(cdl + cdr + EPSV);
  float gfd = (dr - dl) * 0.5f * rcpf_(height + EPSV);        // gx_from_ds
  float den = fmaf(wpc, cgv, cfd);                            // wp*cgx + cgx_from_ds
  float num = fmaf(wpc * cgv, gxv, cfd * gfd);
  float gprop = num * rcpf_(den + EPSV);
  float cprop = den * inv_wp1;
  Pv = cprop;
  Vv = cprop * gprop;
}

// ---------------------------------------------------------------------------
// Fully fused, BARRIER-FREE kernel.
//
// R5/R6/R7 (barrier-phased fusion) all landed 167-200us with VALU-busy ~72us
// constant and ~60% dead time: all 8 waves of a block stall together at each
// barrier, and 4 blocks/CU can't fill the gaps. VALU floor for this op is
// ~60us (1x1 conv 27 + depthwise 11 + pointwise ~20) — the entire remaining
// gap is idle time, so this version removes the synchronization entirely:
//
//   - Each WAVE owns a 16x4 output tile with a wave-PRIVATE 8x24 halo region
//     in LDS (2 x 1536 B, double-buffered). Staging is wave-internal, so the
//     only fence needed is s_waitcnt lgkmcnt(0) (same-wave DS ops are
//     processed in order). NO __syncthreads in the kernel.
//   - Waves are fully independent -> uncorrelated phases -> each wave's
//     LDS/VMEM latency is covered by other waves' VALU work.
//   - Per channel: stage (4 px pointwise, lanes<48; 2 ds_write_b128) ->
//     issue next channel's 4 f4 global loads -> lgkmcnt(0) -> 25 b64 conv
//     reads + 50 FMA -> 64-FMA rank-1 acc update.
//   - Costs accepted: 3x pointwise redundancy (192 staged px / 64 outputs,
//     +~10us VALU), ~4-way LDS conflicts on conv reads (LDS pipe ~34us,
//     still < VALU and now hideable).
//   - Epilogue stores: 16-wide rows -> 64 B contiguous per row, coalesced.
// VGPR target <=128 (launch_bounds(256,4)) -> 16 waves/CU; grid 2048 blocks
// = 8/CU issued vs 4 resident (backfill).
// ---------------------------------------------------------------------------
__global__ __launch_bounds__(NT, 4) void fused_kernel(
    const float* __restrict__ dp, const float* __restrict__ cdp,
    const float* __restrict__ gxp, const float* __restrict__ cgxp,
    const float* __restrict__ ws, const float* __restrict__ bias,
    float* __restrict__ out) {
  __shared__ __align__(16) char shb[NWAVE * WLDS];  // 12,288 B

  const int t = threadIdx.x;
  const int wid = t >> 6;
  const int lane = t & 63;
  char* wbase = shb + wid * WLDS;

  // ---- tile mapping: XCD-striped images, row-major tile quads ----
  // virt = (wg&7)*256 + wg>>3 : bijective over 2048; img = virt>>8;
  // rem -> (ty, qx); wave wid takes tx = qx*4 + wid.
  const int wg = blockIdx.x;
  const int virt = (wg & 7) * (NBLK / 8) + (wg >> 3);
  const int b = virt >> 8;
  const int rem = virt & 255;
  const int ty = rem >> 2;                   // 0..63
  const int qx = rem & 3;                    // 0..3
  const int tx = qx * 4 + wid;               // 0..15
  const int w0 = tx * WTW, h0 = ty * WTH;

  const float Ssw = ws[1856], Scw = ws[1857];
  const float epsS = EPSV * Ssw;
  const float oscale = rcpf_(Ssw) * rcpf_(Scw);

  // ---- staging geometry: 48 f4-tasks (8 rows x 6 quads), lanes 0..47 ----
  const bool sact = lane < 48;
  const int Rr = min(lane, 47) / 6;          // 0..7
  const int qq = min(lane, 47) - 6 * Rr;     // 0..5
  const int gh = h0 + Rr - 2;
  const int ghc = min(max(gh, 0), IMG_H - 1);
  const int gc0 = w0 - 4 + 4 * qq;           // true col of px 0 (may be OOB)
  const int gc0c = min(max(gc0, 0), IMG_W - 4);
  const int goff = ghc * IMG_W + gc0c;       // clamped, 16B aligned
  const bool rowv = (unsigned)gh < (unsigned)IMG_H;
  float msk[4];
  #pragma unroll
  for (int j = 0; j < 4; ++j)
    msk[j] = (rowv & ((unsigned)(gc0 + j) < (unsigned)IMG_W)) ? 1.f : 0.f;
  const int wb = Rr * RSB + qq * 32;         // LDS write byte (16B aligned)

  // ---- conv geometry ----
  const int x = lane & 15, y = lane >> 4;    // px in 16x4 tile
  const int cvb = y * RSB + (x + 2) * 8;     // tap(kr=0,kc=0) byte
  const int pixoff = (h0 + y) * IMG_W + (w0 + x);
  const int planebase = b * NC * PLANE;

  float accN[32], accD[32];
  #pragma unroll
  for (int o = 0; o < 32; ++o) { accN[o] = 0.f; accD[o] = 0.f; }

  // prologue: load channel 0 region quad
  f4 rd, rc, rg, rx;
  if (sact) {
    rd = *(const f4*)(dp + planebase + goff);
    rc = *(const f4*)(cdp + planebase + goff);
    rg = *(const f4*)(gxp + planebase + goff);
    rx = *(const f4*)(cgxp + planebase + goff);
  }

  #pragma unroll 1
  for (int c = 0; c < NC; ++c) {
    char* buf = wbase + (c & 1) * BUFB;
    const float wpc = ws[c];
    const float inv_wp1 = rcpf_(wpc + 1.0f);

    // stage: pointwise for 4 px -> interleaved {P,V} pairs, 2 b128 writes
    if (sact) {
      float P[4], V[4];
      #pragma unroll
      for (int j = 0; j < 4; ++j)
        pointwise_pv(rd[j], rc[j] * msk[j], rg[j], rx[j] * msk[j], gc0 + j,
                     wpc, inv_wp1, P[j], V[j]);
      f4 wv1; wv1[0] = P[0]; wv1[1] = V[0]; wv1[2] = P[1]; wv1[3] = V[1];
      f4 wv2; wv2[0] = P[2]; wv2[1] = V[2]; wv2[2] = P[3]; wv2[3] = V[3];
      *(f4*)(buf + wb) = wv1;
      *(f4*)(buf + wb + 16) = wv2;
    }

    // prefetch next channel (latency covered by this channel's conv+acc)
    if ((c + 1 < NC) & sact) {
      const int pb = planebase + (c + 1) * PLANE + goff;
      rd = *(const f4*)(dp + pb);
      rc = *(const f4*)(cdp + pb);
      rg = *(const f4*)(gxp + pb);
      rx = *(const f4*)(cgxp + pb);
    }

    // wave-local fence: this wave's LDS writes complete; no barrier needed
    // (LDS region is wave-private; same-wave DS ops are in-order).
    asm volatile("s_waitcnt lgkmcnt(0)" ::: "memory");

    // depthwise 5x5 at this lane's pixel (25 b64 reads, interleaved {P,V})
    const char* bp = buf + cvb;
    const float* swc = ws + 32 + c * 25;
    float Dc = 0.f, Nc = 0.f;
    #pragma unroll
    for (int kr = 0; kr < 5; ++kr) {
      #pragma unroll
      for (int kc = 0; kc < 5; ++kc) {
        const f2 pv = *(const f2*)(bp + kr * RSB + kc * 8);
        const float wv = swc[kr * 5 + kc];
        Dc = fmaf(wv, pv[0], Dc);
        Nc = fmaf(wv, pv[1], Nc);
      }
    }

    // rank-1 update of the 1x1-conv accumulators (static indices)
    const float* cwc = ws + 832 + c * NO;
    #pragma unroll
    for (int o = 0; o < 32; ++o) {
      accD[o] = fmaf(cwc[o], Dc, accD[o]);
      accN[o] = fmaf(cwc[o], Nc, accN[o]);
    }
  }

  // epilogue: folded normalization + coalesced store (16-wide rows = 64 B)
  //   gx[o]  = accN[o]/(accD[o] + EPS*Ssw) + bias[o]
  //   cgx[o] = accD[o]/(Ssw*Scw)
  const int ob = b * NO * PLANE + pixoff;
  #pragma unroll
  for (int o = 0; o < 32; ++o) {
    const float g = fmaf(accN[o], rcpf_(accD[o] + epsS), bias[o]);
    const float cg = accD[o] * oscale;
    out[ob + o * PLANE] = g;
    out[HALF + ob + o * PLANE] = cg;
  }
}

extern "C" void kernel_launch(void* const* d_in, const int* in_sizes, int n_in,
                              void* d_out, int out_size, void* d_ws, size_t ws_size,
                              hipStream_t stream) {
  const float* dp   = (const float*)d_in[0];
  const float* cdp  = (const float*)d_in[1];
  const float* gxp  = (const float*)d_in[2];
  const float* cgxp = (const float*)d_in[3];
  const float* wp   = (const float*)d_in[4];
  const float* sw   = (const float*)d_in[5];
  const float* cw   = (const float*)d_in[6];
  const float* bias = (const float*)d_in[7];
  float* out = (float*)d_out;
  float* ws  = (float*)d_ws;

  weights_kernel<<<1, 256, 0, stream>>>(wp, sw, cw, ws);
  fused_kernel<<<NBLK, NT, 0, stream>>>(dp, cdp, gxp, cgxp, ws, bias, out);
}